// Round 13
// baseline (85431.451 us; speedup 1.0000x reference)
//
#include <hip/hip_runtime.h>
#include <math.h>

// GradPooling: x (32,56,56,256) f32 NHWC, pool=3 stride=2 pad=2 -> (32,29,29,256)
// gate = d_center > theta_final; theta_final = v1 = smallest d_center > theta_m8;
// theta_m8 = mod-8-chain strict f32 fold of flat dcol (bit-exact vs ref; R9-R12).
// R13: barrier-free fold — one wave streams chain-major val_t straight from
// global with a 6-buffer static register pipeline. Only the dep-add chain remains.

#define NB 32
#define H 56
#define W 56
#define C 256
#define OH 29
#define OW 29
#define NTOT 62005248u
#define K_CH 7750656u     // per-chain length = NTOT/8
#define NMB 242208        // micro-blocks of 32 elems (8 float4) per chain
#define GITER 40368       // NMB / 6 exactly
// fallback tiling (R10-validated)
#define QT 1024
#define TILE_F (QT * 8)
#define NTILES 7569

__device__ __forceinline__ float xat(const float* __restrict__ x, int n, int r, int s, int c) {
    if ((unsigned)r < (unsigned)H && (unsigned)s < (unsigned)W)
        return x[(((size_t)n * H + r) * W + s) * C + c];
    return 0.f;
}

// dcol flat element f (C-order (9,32,256,29,29)) -> f32, elementwise = ref
__device__ __forceinline__ float dcol_val(const float* __restrict__ x, unsigned f) {
    unsigned t  = f / 6889472u;  unsigned r = f - t * 6889472u;   // 32*256*841
    unsigned n  = r / 215296u;   r -= n * 215296u;                // 256*841
    unsigned c  = r / 841u;      r -= c * 841u;
    unsigned oh = r / 29u;       unsigned ow = r - oh * 29u;
    int y  = (int)(t / 3u);
    int xx = (int)(t - 3u * (t / 3u));
    int i = y + 2 * (int)oh - 2;
    int j = xx + 2 * (int)ow - 2;
    if (i < 0 || j < 0) return 0.f;   // dp zero padding
    float a = xat(x, n, i, j, c);
    float b = xat(x, n, i - 2, j, c);
    float e = xat(x, n, i, j - 2, c);
    return 2.0f * (fabsf(a - b) + fabsf(a - e));
}

// ---- chain-major materialization: val_t[r*K_CH + q] = dcol_val(8q + r) ----
__global__ __launch_bounds__(256) void k_dcolT(const float* __restrict__ x,
                                               float* __restrict__ valt) {
    unsigned q = (unsigned)(blockIdx.x * 256 + threadIdx.x);
    if (q >= K_CH) return;
#pragma unroll
    for (unsigned r = 0; r < 8; ++r) {
        valt[(size_t)r * K_CH + q] = dcol_val(x, q * 8u + r);
    }
}

// ---- barrier-free global-streaming fold, 6-buffer register pipeline ----
#define DECLB(B) float4 B##0, B##1, B##2, B##3, B##4, B##5, B##6, B##7;
#define LD(B)  do { B##0 = p[0]; B##1 = p[1]; B##2 = p[2]; B##3 = p[3]; \
                    B##4 = p[4]; B##5 = p[5]; B##6 = p[6]; B##7 = p[7]; p += 8; } while (0)
#define CS4(v) do { acc += (v).x; acc += (v).y; acc += (v).z; acc += (v).w; } while (0)
#define CS(B)  do { CS4(B##0); CS4(B##1); CS4(B##2); CS4(B##3); \
                    CS4(B##4); CS4(B##5); CS4(B##6); CS4(B##7); } while (0)

__global__ __launch_bounds__(64) void k_fold8g(const float* __restrict__ valt,
                                               float* __restrict__ thr_m8) {
    const int lane = threadIdx.x;
    const int r = lane & 7;
    const float4* p = reinterpret_cast<const float4*>(valt + (size_t)r * K_CH);

    DECLB(A) DECLB(B) DECLB(Cc) DECLB(D) DECLB(E) DECLB(F)
    float acc = 0.f;

    // prologue: 5 buffers in flight
    LD(A); LD(B); LD(Cc); LD(D); LD(E);

    for (int g = 0; g < GITER; ++g) {
        LD(F);  CS(A);   // consume mb 6g+0 while 5 buffers outstanding
        LD(A);  CS(B);
        LD(B);  CS(Cc);
        LD(Cc); CS(D);
        LD(D);  CS(E);
        LD(E);  CS(F);
    }
    // note: last iteration's LD(A..E) read <=5 mbs past the chain end into
    // workspace slack -- loaded but never consumed.

    // exact same horizontal association as the validated fold
    float t1 = acc + __shfl(acc, lane + 4, 64);
    float t2 = t1 + __shfl(t1, lane + 2, 64);
    float t3 = t2 + __shfl(t2, lane + 1, 64);
    if (lane == 0) thr_m8[0] = t3 / 62005248.0f;
}

// ---- fallback fold (R10-validated): on-the-fly producers, if ws too small ----
__global__ __launch_bounds__(1024) void k_fold8(const float* __restrict__ x,
                                                float* __restrict__ thr_m8) {
    __shared__ float buf[2][TILE_F];
    const int tid = threadIdx.x;
    if (tid >= 64) {
        for (int idx = tid - 64; idx < TILE_F; idx += 960)
            buf[0][idx] = dcol_val(x, (unsigned)idx);
    }
    __syncthreads();
    float acc = 0.f;
    const int r = tid & 7;
    for (int t = 0; t < NTILES; ++t) {
        if (tid >= 64) {
            if (t + 1 < NTILES) {
                const unsigned base = (unsigned)(t + 1) * TILE_F;
                float* nb = buf[(t + 1) & 1];
                for (int idx = tid - 64; idx < TILE_F; idx += 960)
                    nb[idx] = dcol_val(x, base + (unsigned)idx);
            }
        } else {
            const float* bp = buf[t & 1];
#pragma unroll 16
            for (int qq = 0; qq < QT; ++qq)
                acc += bp[8 * qq + r];
        }
        __syncthreads();
    }
    if (tid < 64) {
        float t1 = acc + __shfl(acc, tid + 4, 64);
        float t2 = t1 + __shfl(t1, tid + 2, 64);
        float t3 = t2 + __shfl(t2, tid + 1, 64);
        if (tid == 0) thr_m8[0] = t3 / 62005248.0f;
    }
}

__global__ void k_cinit(unsigned* cand) { cand[0] = 0x7F800000u; }  // +inf

// smallest d_center strictly above thr_m8 (uint atomicMin == float min for d>=0)
__global__ __launch_bounds__(256) void k_cand(const float* __restrict__ x,
                                              const float* __restrict__ thr_m8,
                                              unsigned* __restrict__ cand) {
    const float thr = thr_m8[0];
    const int bid = blockIdx.x;           // (n*OH + oh)*OW + ow
    const int ow = bid % OW;
    const int oh = (bid / OW) % OH;
    const int n = bid / (OW * OH);
    if (oh == 0 || ow == 0) return;
    const int c = threadIdx.x;
    const int r = 2 * oh - 1, s = 2 * ow - 1;
    float a = xat(x, n, r, s, c);
    float b = xat(x, n, r - 2, s, c);
    float e = xat(x, n, r, s - 2, c);
    float d = 2.0f * (fabsf(a - b) + fabsf(a - e));
    if (d > thr) atomicMin(cand, __float_as_uint(d));
}

__global__ void k_sel(const float* __restrict__ thr_m8,
                      const unsigned* __restrict__ cand,
                      float* __restrict__ thrf) {
    float v = __uint_as_float(cand[0]);
    thrf[0] = isinf(v) ? thr_m8[0] : v;   // theta = v1 (gate is strict >)
}

__device__ __forceinline__ float4 ldx(const float* __restrict__ xb, int r, int s, int c) {
    if ((unsigned)r < (unsigned)H && (unsigned)s < (unsigned)W) {
        return *reinterpret_cast<const float4*>(xb + ((size_t)(r * W + s)) * C + c);
    }
    return make_float4(0.f, 0.f, 0.f, 0.f);
}

__device__ __forceinline__ float getl(const float4& v, int l) {
    return l == 0 ? v.x : (l == 1 ? v.y : (l == 2 ? v.z : v.w));
}

__global__ __launch_bounds__(256) void k_pool(const float* __restrict__ x,
                                              const float* __restrict__ thrf,
                                              float* __restrict__ out) {
    const float thresh = thrf[0];
    const int bid = blockIdx.x;            // ((n*OH)+oh)*8 + owg
    const int owg = bid & 7;
    const int oh = (bid >> 3) % OH;
    const int n = (bid >> 3) / OH;
    const int t = threadIdx.x;
    const int cq = (t & 63) << 2;
    const int ow = (owg << 2) + (t >> 6);
    if (ow >= OW) return;
    const float* xb = x + (size_t)n * (H * W * C);
    const int r0 = 2 * oh - 2, s0 = 2 * ow - 2;

    float4 v[3][3];
#pragma unroll
    for (int yy = 0; yy < 3; ++yy)
#pragma unroll
        for (int xx = 0; xx < 3; ++xx)
            v[yy][xx] = ldx(xb, r0 + yy, s0 + xx, cq);

    float4 b4 = ldx(xb, r0 - 1, s0 + 1, cq);
    float4 e4 = ldx(xb, r0 + 1, s0 - 1, cq);
    float4 a4 = v[1][1];
    const bool cen_ok = (oh >= 1) && (ow >= 1);

    float outv[4];
#pragma unroll
    for (int l = 0; l < 4; ++l) {
        float m = -INFINITY, s = 0.f;
#pragma unroll
        for (int yy = 0; yy < 3; ++yy)
#pragma unroll
            for (int xx = 0; xx < 3; ++xx) {
                float q = getl(v[yy][xx], l);
                m = fmaxf(m, q);
                s += q;
            }
        float mean = s / 9.0f;
        float cen = 0.f;
        if (cen_ok) {
            float a = getl(a4, l), b = getl(b4, l), e = getl(e4, l);
            cen = 2.0f * (fabsf(a - b) + fabsf(a - e));
        }
        outv[l] = (cen > thresh) ? m : mean;
    }
    float4 o = make_float4(outv[0], outv[1], outv[2], outv[3]);
    *reinterpret_cast<float4*>(out + ((size_t)((n * OH + oh) * OW + ow)) * C + cq) = o;
}

extern "C" void kernel_launch(void* const* d_in, const int* in_sizes, int n_in,
                              void* d_out, int out_size, void* d_ws, size_t ws_size,
                              hipStream_t stream) {
    const float* x = (const float*)d_in[0];
    float* out = (float*)d_out;
    float* thr_m8 = (float*)d_ws;              // [0]
    unsigned* cand = (unsigned*)d_ws + 1;      // [1]
    float* thrf = (float*)d_ws + 2;            // [2]
    float* valt = (float*)d_ws + 16;           // 64B-aligned chain-major array
    const size_t need = (16ull + NTOT + 8192ull) * sizeof(float);  // +tail slack

    if (ws_size >= need) {
        k_dcolT<<<(K_CH + 255) / 256, 256, 0, stream>>>(x, valt);
        k_fold8g<<<1, 64, 0, stream>>>(valt, thr_m8);
    } else {
        k_fold8<<<1, 1024, 0, stream>>>(x, thr_m8);
    }
    k_cinit<<<1, 1, 0, stream>>>(cand);
    k_cand<<<NB * OH * OW, 256, 0, stream>>>(x, thr_m8, cand);
    k_sel<<<1, 1, 0, stream>>>(thr_m8, cand, thrf);
    k_pool<<<NB * OH * 8, 256, 0, stream>>>(x, thrf, out);
}

// Round 14
// 37932.648 us; speedup vs baseline: 2.2522x; 2.2522x over previous
//
#include <hip/hip_runtime.h>
#include <math.h>

// GradPooling: x (32,56,56,256) f32 NHWC, pool=3 stride=2 pad=2 -> (32,29,29,256)
// gate = d_center > theta_final; theta_final = v1 = smallest d_center > theta_m8;
// theta_m8 = mod-8-chain strict f32 fold of flat dcol (bit-exact vs ref; R9-R13).
// R14: single-wave zero-barrier fold. global_load_lds DMA (16B) double-buffers
// tiles; consumer wave does the strict dep-add chain; vmcnt-counted waits only.

#define NB 32
#define H 56
#define W 56
#define C 256
#define OH 29
#define OW 29
#define NTOT 62005248u
#define K_CH 7750656u       // per-chain length = NTOT/8
#define TP 512              // per-chain elems per tile
#define TROW 516            // LDS row stride in floats (2064B -> banks 4r, conflict-free)
#define NT3 15138           // K_CH / TP exactly
// fallback tiling (R10-validated)
#define QT 1024
#define TILE_F (QT * 8)
#define NTILES 7569

__device__ __forceinline__ float xat(const float* __restrict__ x, int n, int r, int s, int c) {
    if ((unsigned)r < (unsigned)H && (unsigned)s < (unsigned)W)
        return x[(((size_t)n * H + r) * W + s) * C + c];
    return 0.f;
}

// dcol flat element f (C-order (9,32,256,29,29)) -> f32, elementwise = ref
__device__ __forceinline__ float dcol_val(const float* __restrict__ x, unsigned f) {
    unsigned t  = f / 6889472u;  unsigned r = f - t * 6889472u;   // 32*256*841
    unsigned n  = r / 215296u;   r -= n * 215296u;                // 256*841
    unsigned c  = r / 841u;      r -= c * 841u;
    unsigned oh = r / 29u;       unsigned ow = r - oh * 29u;
    int y  = (int)(t / 3u);
    int xx = (int)(t - 3u * (t / 3u));
    int i = y + 2 * (int)oh - 2;
    int j = xx + 2 * (int)ow - 2;
    if (i < 0 || j < 0) return 0.f;   // dp zero padding
    float a = xat(x, n, i, j, c);
    float b = xat(x, n, i - 2, j, c);
    float e = xat(x, n, i, j - 2, c);
    return 2.0f * (fabsf(a - b) + fabsf(a - e));
}

// ---- tile-row-major materialization:
// val2[((q/TP)*8 + r)*TP + q%TP] = dcol_val(8q + r)  (tile t = 8 rows of TP)
__global__ __launch_bounds__(256) void k_dcolT2(const float* __restrict__ x,
                                                float* __restrict__ val2) {
    unsigned q = (unsigned)(blockIdx.x * 256 + threadIdx.x);
    if (q >= K_CH) return;
    const unsigned t = q / TP, c = q % TP;
#pragma unroll
    for (unsigned r = 0; r < 8; ++r) {
        val2[((size_t)t * 8u + r) * TP + c] = dcol_val(x, q * 8u + r);
    }
}

__device__ __forceinline__ void async_load1k(const float* __restrict__ g, float* lds) {
    // 64 lanes x 16B: lds[lane*16B] = g[lane*16B]
    __builtin_amdgcn_global_load_lds(
        (const __attribute__((address_space(1))) void*)g,
        (__attribute__((address_space(3))) void*)lds, 16, 0, 0);
}

// issue the 16 DMA ops for tile t into buffer nb (per-row: 2 x 1KB chunks)
__device__ __forceinline__ void issue_tile(const float* __restrict__ val2,
                                           float* __restrict__ buf, int t, int lane) {
    const float* gt = val2 + (size_t)t * (8 * TP);
#pragma unroll
    for (int r = 0; r < 8; ++r) {
#pragma unroll
        for (int k = 0; k < 2; ++k) {
            async_load1k(gt + r * TP + k * 256 + lane * 4, buf + r * TROW + k * 256);
        }
    }
}

// ---- single-wave fold: DMA double-buffer, zero barriers ----
__global__ __launch_bounds__(64) void k_fold8l(const float* __restrict__ val2,
                                               float* __restrict__ thr_m8) {
    __shared__ float buf[2][8 * TROW];
    const int lane = threadIdx.x;
    const int r = lane & 7;

    issue_tile(val2, buf[0], 0, lane);
    asm volatile("s_waitcnt vmcnt(0)" ::: "memory");
    __builtin_amdgcn_sched_barrier(0);

    float acc = 0.f;
    for (int t = 0; t < NT3; ++t) {
        if (t + 1 < NT3) issue_tile(val2, buf[(t + 1) & 1], t + 1, lane);
        __builtin_amdgcn_sched_barrier(0);

        const float4* fp = reinterpret_cast<const float4*>(&buf[t & 1][r * TROW]);
        // 512 elems = 16 micro-blocks of 32 (8 x ds_read_b128), 2-deep pipeline
        float4 c0, c1, c2, c3, c4, c5, c6, c7;
        float4 n0, n1, n2, n3, n4, n5, n6, n7;
        c0 = fp[0]; c1 = fp[1]; c2 = fp[2]; c3 = fp[3];
        c4 = fp[4]; c5 = fp[5]; c6 = fp[6]; c7 = fp[7];
#pragma unroll 4
        for (int mb = 0; mb < 16; ++mb) {
            if (mb + 1 < 16) {
                const float4* np = fp + (mb + 1) * 8;
                n0 = np[0]; n1 = np[1]; n2 = np[2]; n3 = np[3];
                n4 = np[4]; n5 = np[5]; n6 = np[6]; n7 = np[7];
            }
            acc += c0.x; acc += c0.y; acc += c0.z; acc += c0.w;
            acc += c1.x; acc += c1.y; acc += c1.z; acc += c1.w;
            acc += c2.x; acc += c2.y; acc += c2.z; acc += c2.w;
            acc += c3.x; acc += c3.y; acc += c3.z; acc += c3.w;
            acc += c4.x; acc += c4.y; acc += c4.z; acc += c4.w;
            acc += c5.x; acc += c5.y; acc += c5.z; acc += c5.w;
            acc += c6.x; acc += c6.y; acc += c6.z; acc += c6.w;
            acc += c7.x; acc += c7.y; acc += c7.z; acc += c7.w;
            c0 = n0; c1 = n1; c2 = n2; c3 = n3;
            c4 = n4; c5 = n5; c6 = n6; c7 = n7;
        }
        // next tile's DMA (issued above) has had a full consume (~2048cy) to land
        asm volatile("s_waitcnt vmcnt(0)" ::: "memory");
        __builtin_amdgcn_sched_barrier(0);
    }

    // exact same horizontal association as the validated fold
    float t1 = acc + __shfl(acc, lane + 4, 64);
    float t2 = t1 + __shfl(t1, lane + 2, 64);
    float t3 = t2 + __shfl(t2, lane + 1, 64);
    if (lane == 0) thr_m8[0] = t3 / 62005248.0f;
}

// ---- fallback fold (R10-validated): on-the-fly producers, if ws too small ----
__global__ __launch_bounds__(1024) void k_fold8(const float* __restrict__ x,
                                                float* __restrict__ thr_m8) {
    __shared__ float buf[2][TILE_F];
    const int tid = threadIdx.x;
    if (tid >= 64) {
        for (int idx = tid - 64; idx < TILE_F; idx += 960)
            buf[0][idx] = dcol_val(x, (unsigned)idx);
    }
    __syncthreads();
    float acc = 0.f;
    const int r = tid & 7;
    for (int t = 0; t < NTILES; ++t) {
        if (tid >= 64) {
            if (t + 1 < NTILES) {
                const unsigned base = (unsigned)(t + 1) * TILE_F;
                float* nb = buf[(t + 1) & 1];
                for (int idx = tid - 64; idx < TILE_F; idx += 960)
                    nb[idx] = dcol_val(x, base + (unsigned)idx);
            }
        } else {
            const float* bp = buf[t & 1];
#pragma unroll 16
            for (int qq = 0; qq < QT; ++qq)
                acc += bp[8 * qq + r];
        }
        __syncthreads();
    }
    if (tid < 64) {
        float t1 = acc + __shfl(acc, tid + 4, 64);
        float t2 = t1 + __shfl(t1, tid + 2, 64);
        float t3 = t2 + __shfl(t2, tid + 1, 64);
        if (tid == 0) thr_m8[0] = t3 / 62005248.0f;
    }
}

__global__ void k_cinit(unsigned* cand) { cand[0] = 0x7F800000u; }  // +inf

// smallest d_center strictly above thr_m8 (uint atomicMin == float min for d>=0)
__global__ __launch_bounds__(256) void k_cand(const float* __restrict__ x,
                                              const float* __restrict__ thr_m8,
                                              unsigned* __restrict__ cand) {
    const float thr = thr_m8[0];
    const int bid = blockIdx.x;           // (n*OH + oh)*OW + ow
    const int ow = bid % OW;
    const int oh = (bid / OW) % OH;
    const int n = bid / (OW * OH);
    if (oh == 0 || ow == 0) return;
    const int c = threadIdx.x;
    const int r = 2 * oh - 1, s = 2 * ow - 1;
    float a = xat(x, n, r, s, c);
    float b = xat(x, n, r - 2, s, c);
    float e = xat(x, n, r, s - 2, c);
    float d = 2.0f * (fabsf(a - b) + fabsf(a - e));
    if (d > thr) atomicMin(cand, __float_as_uint(d));
}

__global__ void k_sel(const float* __restrict__ thr_m8,
                      const unsigned* __restrict__ cand,
                      float* __restrict__ thrf) {
    float v = __uint_as_float(cand[0]);
    thrf[0] = isinf(v) ? thr_m8[0] : v;   // theta = v1 (gate is strict >)
}

__device__ __forceinline__ float4 ldx(const float* __restrict__ xb, int r, int s, int c) {
    if ((unsigned)r < (unsigned)H && (unsigned)s < (unsigned)W) {
        return *reinterpret_cast<const float4*>(xb + ((size_t)(r * W + s)) * C + c);
    }
    return make_float4(0.f, 0.f, 0.f, 0.f);
}

__device__ __forceinline__ float getl(const float4& v, int l) {
    return l == 0 ? v.x : (l == 1 ? v.y : (l == 2 ? v.z : v.w));
}

__global__ __launch_bounds__(256) void k_pool(const float* __restrict__ x,
                                              const float* __restrict__ thrf,
                                              float* __restrict__ out) {
    const float thresh = thrf[0];
    const int bid = blockIdx.x;            // ((n*OH)+oh)*8 + owg
    const int owg = bid & 7;
    const int oh = (bid >> 3) % OH;
    const int n = (bid >> 3) / OH;
    const int t = threadIdx.x;
    const int cq = (t & 63) << 2;
    const int ow = (owg << 2) + (t >> 6);
    if (ow >= OW) return;
    const float* xb = x + (size_t)n * (H * W * C);
    const int r0 = 2 * oh - 2, s0 = 2 * ow - 2;

    float4 v[3][3];
#pragma unroll
    for (int yy = 0; yy < 3; ++yy)
#pragma unroll
        for (int xx = 0; xx < 3; ++xx)
            v[yy][xx] = ldx(xb, r0 + yy, s0 + xx, cq);

    float4 b4 = ldx(xb, r0 - 1, s0 + 1, cq);
    float4 e4 = ldx(xb, r0 + 1, s0 - 1, cq);
    float4 a4 = v[1][1];
    const bool cen_ok = (oh >= 1) && (ow >= 1);

    float outv[4];
#pragma unroll
    for (int l = 0; l < 4; ++l) {
        float m = -INFINITY, s = 0.f;
#pragma unroll
        for (int yy = 0; yy < 3; ++yy)
#pragma unroll
            for (int xx = 0; xx < 3; ++xx) {
                float q = getl(v[yy][xx], l);
                m = fmaxf(m, q);
                s += q;
            }
        float mean = s / 9.0f;
        float cen = 0.f;
        if (cen_ok) {
            float a = getl(a4, l), b = getl(b4, l), e = getl(e4, l);
            cen = 2.0f * (fabsf(a - b) + fabsf(a - e));
        }
        outv[l] = (cen > thresh) ? m : mean;
    }
    float4 o = make_float4(outv[0], outv[1], outv[2], outv[3]);
    *reinterpret_cast<float4*>(out + ((size_t)((n * OH + oh) * OW + ow)) * C + cq) = o;
}

extern "C" void kernel_launch(void* const* d_in, const int* in_sizes, int n_in,
                              void* d_out, int out_size, void* d_ws, size_t ws_size,
                              hipStream_t stream) {
    const float* x = (const float*)d_in[0];
    float* out = (float*)d_out;
    float* thr_m8 = (float*)d_ws;              // [0]
    unsigned* cand = (unsigned*)d_ws + 1;      // [1]
    float* thrf = (float*)d_ws + 2;            // [2]
    float* val2 = (float*)d_ws + 16;           // 64B-aligned tile-row-major array
    const size_t need = (16ull + NTOT) * sizeof(float);

    if (ws_size >= need) {
        k_dcolT2<<<(K_CH + 255) / 256, 256, 0, stream>>>(x, val2);
        k_fold8l<<<1, 64, 0, stream>>>(val2, thr_m8);
    } else {
        k_fold8<<<1, 1024, 0, stream>>>(x, thr_m8);
    }
    k_cinit<<<1, 1, 0, stream>>>(cand);
    k_cand<<<NB * OH * OW, 256, 0, stream>>>(x, thr_m8, cand);
    k_sel<<<1, 1, 0, stream>>>(thr_m8, cand, thrf);
    k_pool<<<NB * OH * 8, 256, 0, stream>>>(x, thrf, out);
}

// Round 15
// 32491.016 us; speedup vs baseline: 2.6294x; 1.1675x over previous
//
#include <hip/hip_runtime.h>
#include <math.h>

// GradPooling: x (32,56,56,256) f32 NHWC, pool=3 stride=2 pad=2 -> (32,29,29,256)
// gate = d_center > theta_final; theta_final = v1 = smallest d_center > theta_m8;
// theta_m8 = mod-8-chain strict f32 fold of flat dcol (bit-exact vs ref; R9-R14).
// R15: R12's validated producer/consumer fold with 3.6x bigger tiles
// (T_PER 512 -> 1856, exact divisor of K_CH) to amortize barrier overhead.

#define NB 32
#define H 56
#define W 56
#define C 256
#define OH 29
#define OW 29
#define NTOT 62005248u
#define K_CH 7750656u       // per-chain length = NTOT/8 = 2^10 * 3^2 * 29^2
#define TP 1856             // per-chain elems per tile (2^6 * 29, divides K_CH)
#define TROW 1860           // LDS row stride floats: bank 4r per row, 16B aligned
#define NT4 4176            // K_CH / TP exactly
#define T_F4 3712           // float4s per tile = 8*TP/4
#define R_F4 464            // float4s per row = TP/4
#define NMB_T 58            // micro-blocks (32 elems) per tile = TP/32
// fallback tiling (R10-validated)
#define QT 1024
#define TILE_F (QT * 8)
#define NTILES 7569

__device__ __forceinline__ float xat(const float* __restrict__ x, int n, int r, int s, int c) {
    if ((unsigned)r < (unsigned)H && (unsigned)s < (unsigned)W)
        return x[(((size_t)n * H + r) * W + s) * C + c];
    return 0.f;
}

// dcol flat element f (C-order (9,32,256,29,29)) -> f32, elementwise = ref
__device__ __forceinline__ float dcol_val(const float* __restrict__ x, unsigned f) {
    unsigned t  = f / 6889472u;  unsigned r = f - t * 6889472u;   // 32*256*841
    unsigned n  = r / 215296u;   r -= n * 215296u;                // 256*841
    unsigned c  = r / 841u;      r -= c * 841u;
    unsigned oh = r / 29u;       unsigned ow = r - oh * 29u;
    int y  = (int)(t / 3u);
    int xx = (int)(t - 3u * (t / 3u));
    int i = y + 2 * (int)oh - 2;
    int j = xx + 2 * (int)ow - 2;
    if (i < 0 || j < 0) return 0.f;   // dp zero padding
    float a = xat(x, n, i, j, c);
    float b = xat(x, n, i - 2, j, c);
    float e = xat(x, n, i, j - 2, c);
    return 2.0f * (fabsf(a - b) + fabsf(a - e));
}

// ---- tile-row-major materialization:
// val2[((q/TP)*8 + r)*TP + q%TP] = dcol_val(8q + r)
__global__ __launch_bounds__(256) void k_dcolT2(const float* __restrict__ x,
                                                float* __restrict__ val2) {
    unsigned q = (unsigned)(blockIdx.x * 256 + threadIdx.x);
    if (q >= K_CH) return;
    const unsigned t = q / TP, c = q % TP;
#pragma unroll
    for (unsigned r = 0; r < 8; ++r) {
        val2[((size_t)t * 8u + r) * TP + c] = dcol_val(x, q * 8u + r);
    }
}

// producers copy tile t (row-major [8][R_F4] float4) into padded LDS tile
__device__ __forceinline__ void fill_tile(const float* __restrict__ val2,
                                          float* __restrict__ dst, int t, int tid) {
    const float4* src = reinterpret_cast<const float4*>(val2) + (size_t)t * T_F4;
    float4* d4 = reinterpret_cast<float4*>(dst);
    for (int i4 = tid - 64; i4 < T_F4; i4 += 448) {
        const int row = i4 / R_F4;
        const int c4  = i4 - row * R_F4;
        d4[row * (TROW / 4) + c4] = src[i4];
    }
}

// ---- producer/consumer fold (R12 structure, bigger tiles) ----
__global__ __launch_bounds__(512) void k_fold8t(const float* __restrict__ val2,
                                                float* __restrict__ thr_m8) {
    __shared__ float buf[2][8 * TROW];
    const int tid = threadIdx.x;

    if (tid >= 64) fill_tile(val2, buf[0], 0, tid);
    __syncthreads();

    float acc = 0.f;
    const int r = tid & 7;

    for (int t = 0; t < NT4; ++t) {
        if (tid >= 64) {
            if (t + 1 < NT4) fill_tile(val2, buf[(t + 1) & 1], t + 1, tid);
        } else {
            __builtin_amdgcn_s_setprio(1);
            const float4* fp = reinterpret_cast<const float4*>(&buf[t & 1][r * TROW]);
            // NMB_T micro-blocks of 32 (8 x ds_read_b128), 2-deep register pipeline
            float4 c0, c1, c2, c3, c4, c5, c6, c7;
            float4 n0, n1, n2, n3, n4, n5, n6, n7;
            c0 = fp[0]; c1 = fp[1]; c2 = fp[2]; c3 = fp[3];
            c4 = fp[4]; c5 = fp[5]; c6 = fp[6]; c7 = fp[7];
#pragma unroll 2
            for (int mb = 0; mb < NMB_T; ++mb) {
                if (mb + 1 < NMB_T) {
                    const float4* np = fp + (mb + 1) * 8;
                    n0 = np[0]; n1 = np[1]; n2 = np[2]; n3 = np[3];
                    n4 = np[4]; n5 = np[5]; n6 = np[6]; n7 = np[7];
                }
                acc += c0.x; acc += c0.y; acc += c0.z; acc += c0.w;
                acc += c1.x; acc += c1.y; acc += c1.z; acc += c1.w;
                acc += c2.x; acc += c2.y; acc += c2.z; acc += c2.w;
                acc += c3.x; acc += c3.y; acc += c3.z; acc += c3.w;
                acc += c4.x; acc += c4.y; acc += c4.z; acc += c4.w;
                acc += c5.x; acc += c5.y; acc += c5.z; acc += c5.w;
                acc += c6.x; acc += c6.y; acc += c6.z; acc += c6.w;
                acc += c7.x; acc += c7.y; acc += c7.z; acc += c7.w;
                c0 = n0; c1 = n1; c2 = n2; c3 = n3;
                c4 = n4; c5 = n5; c6 = n6; c7 = n7;
            }
            __builtin_amdgcn_s_setprio(0);
        }
        __syncthreads();
    }

    if (tid < 64) {
        // exact same horizontal association as the validated fold
        float t1 = acc + __shfl(acc, tid + 4, 64);
        float t2 = t1 + __shfl(t1, tid + 2, 64);
        float t3 = t2 + __shfl(t2, tid + 1, 64);
        if (tid == 0) thr_m8[0] = t3 / 62005248.0f;
    }
}

// ---- fallback fold (R10-validated): on-the-fly producers, if ws too small ----
__global__ __launch_bounds__(1024) void k_fold8(const float* __restrict__ x,
                                                float* __restrict__ thr_m8) {
    __shared__ float buf[2][TILE_F];
    const int tid = threadIdx.x;
    if (tid >= 64) {
        for (int idx = tid - 64; idx < TILE_F; idx += 960)
            buf[0][idx] = dcol_val(x, (unsigned)idx);
    }
    __syncthreads();
    float acc = 0.f;
    const int r = tid & 7;
    for (int t = 0; t < NTILES; ++t) {
        if (tid >= 64) {
            if (t + 1 < NTILES) {
                const unsigned base = (unsigned)(t + 1) * TILE_F;
                float* nb = buf[(t + 1) & 1];
                for (int idx = tid - 64; idx < TILE_F; idx += 960)
                    nb[idx] = dcol_val(x, base + (unsigned)idx);
            }
        } else {
            const float* bp = buf[t & 1];
#pragma unroll 16
            for (int qq = 0; qq < QT; ++qq)
                acc += bp[8 * qq + r];
        }
        __syncthreads();
    }
    if (tid < 64) {
        float t1 = acc + __shfl(acc, tid + 4, 64);
        float t2 = t1 + __shfl(t1, tid + 2, 64);
        float t3 = t2 + __shfl(t2, tid + 1, 64);
        if (tid == 0) thr_m8[0] = t3 / 62005248.0f;
    }
}

__global__ void k_cinit(unsigned* cand) { cand[0] = 0x7F800000u; }  // +inf

// smallest d_center strictly above thr_m8 (uint atomicMin == float min for d>=0)
__global__ __launch_bounds__(256) void k_cand(const float* __restrict__ x,
                                              const float* __restrict__ thr_m8,
                                              unsigned* __restrict__ cand) {
    const float thr = thr_m8[0];
    const int bid = blockIdx.x;           // (n*OH + oh)*OW + ow
    const int ow = bid % OW;
    const int oh = (bid / OW) % OH;
    const int n = bid / (OW * OH);
    if (oh == 0 || ow == 0) return;
    const int c = threadIdx.x;
    const int r = 2 * oh - 1, s = 2 * ow - 1;
    float a = xat(x, n, r, s, c);
    float b = xat(x, n, r - 2, s, c);
    float e = xat(x, n, r, s - 2, c);
    float d = 2.0f * (fabsf(a - b) + fabsf(a - e));
    if (d > thr) atomicMin(cand, __float_as_uint(d));
}

__global__ void k_sel(const float* __restrict__ thr_m8,
                      const unsigned* __restrict__ cand,
                      float* __restrict__ thrf) {
    float v = __uint_as_float(cand[0]);
    thrf[0] = isinf(v) ? thr_m8[0] : v;   // theta = v1 (gate is strict >)
}

__device__ __forceinline__ float4 ldx(const float* __restrict__ xb, int r, int s, int c) {
    if ((unsigned)r < (unsigned)H && (unsigned)s < (unsigned)W) {
        return *reinterpret_cast<const float4*>(xb + ((size_t)(r * W + s)) * C + c);
    }
    return make_float4(0.f, 0.f, 0.f, 0.f);
}

__device__ __forceinline__ float getl(const float4& v, int l) {
    return l == 0 ? v.x : (l == 1 ? v.y : (l == 2 ? v.z : v.w));
}

__global__ __launch_bounds__(256) void k_pool(const float* __restrict__ x,
                                              const float* __restrict__ thrf,
                                              float* __restrict__ out) {
    const float thresh = thrf[0];
    const int bid = blockIdx.x;            // ((n*OH)+oh)*8 + owg
    const int owg = bid & 7;
    const int oh = (bid >> 3) % OH;
    const int n = (bid >> 3) / OH;
    const int t = threadIdx.x;
    const int cq = (t & 63) << 2;
    const int ow = (owg << 2) + (t >> 6);
    if (ow >= OW) return;
    const float* xb = x + (size_t)n * (H * W * C);
    const int r0 = 2 * oh - 2, s0 = 2 * ow - 2;

    float4 v[3][3];
#pragma unroll
    for (int yy = 0; yy < 3; ++yy)
#pragma unroll
        for (int xx = 0; xx < 3; ++xx)
            v[yy][xx] = ldx(xb, r0 + yy, s0 + xx, cq);

    float4 b4 = ldx(xb, r0 - 1, s0 + 1, cq);
    float4 e4 = ldx(xb, r0 + 1, s0 - 1, cq);
    float4 a4 = v[1][1];
    const bool cen_ok = (oh >= 1) && (ow >= 1);

    float outv[4];
#pragma unroll
    for (int l = 0; l < 4; ++l) {
        float m = -INFINITY, s = 0.f;
#pragma unroll
        for (int yy = 0; yy < 3; ++yy)
#pragma unroll
            for (int xx = 0; xx < 3; ++xx) {
                float q = getl(v[yy][xx], l);
                m = fmaxf(m, q);
                s += q;
            }
        float mean = s / 9.0f;
        float cen = 0.f;
        if (cen_ok) {
            float a = getl(a4, l), b = getl(b4, l), e = getl(e4, l);
            cen = 2.0f * (fabsf(a - b) + fabsf(a - e));
        }
        outv[l] = (cen > thresh) ? m : mean;
    }
    float4 o = make_float4(outv[0], outv[1], outv[2], outv[3]);
    *reinterpret_cast<float4*>(out + ((size_t)((n * OH + oh) * OW + ow)) * C + cq) = o;
}

extern "C" void kernel_launch(void* const* d_in, const int* in_sizes, int n_in,
                              void* d_out, int out_size, void* d_ws, size_t ws_size,
                              hipStream_t stream) {
    const float* x = (const float*)d_in[0];
    float* out = (float*)d_out;
    float* thr_m8 = (float*)d_ws;              // [0]
    unsigned* cand = (unsigned*)d_ws + 1;      // [1]
    float* thrf = (float*)d_ws + 2;            // [2]
    float* val2 = (float*)d_ws + 16;           // 64B-aligned tile-row-major array
    const size_t need = (16ull + NTOT) * sizeof(float);

    if (ws_size >= need) {
        k_dcolT2<<<(K_CH + 255) / 256, 256, 0, stream>>>(x, val2);
        k_fold8t<<<1, 512, 0, stream>>>(val2, thr_m8);
    } else {
        k_fold8<<<1, 1024, 0, stream>>>(x, thr_m8);
    }
    k_cinit<<<1, 1, 0, stream>>>(cand);
    k_cand<<<NB * OH * OW, 256, 0, stream>>>(x, thr_m8, cand);
    k_sel<<<1, 1, 0, stream>>>(thr_m8, cand, thrf);
    k_pool<<<NB * OH * 8, 256, 0, stream>>>(x, thrf, out);
}